// Round 1
// baseline (207.836 us; speedup 1.0000x reference)
//
#include <hip/hip_runtime.h>
#include <stdint.h>

// MPS chain contraction, B=32768, L=256, D=16.
// Step GEMM orientation: C[r][n] = sum_q core_p[q][r] * v[q][n]
//   A operand  = core^T (shared, precomputed bf16 hi/lo fragments)
//   B operand  = per-sample state v, split hi/lo packed along K=32
//   C layout: col = lane&15 = sample n (per-lane phi combine is scalar)
// Exact split: (vh+vl)(ch+cl) via 2 MFMAs: [ch|cl]x[vh;vl] + [cl|ch]x[vh;vl]

typedef short  bf16x8 __attribute__((ext_vector_type(8)));
typedef float  f32x4  __attribute__((ext_vector_type(4)));
typedef int    i32x4  __attribute__((ext_vector_type(4)));
typedef unsigned int u32;

#define TMID 254
#define LDS_ROW 20   // dwords per sample row: 16 data + 4 pad (80B, 16B-aligned rows)

__device__ __forceinline__ u32 rne_bump(u32 u){
  // add rounding bias for RNE bf16; result>>16 is the bf16 word,
  // result&0xFFFF0000 is the rounded value as an f32 bit pattern
  return u + 0x7FFFu + ((u >> 16) & 1u);
}

// Prologue: build per-step A-operand fragments from cores_mid (f32).
// fragbuf[(t*4 + f)*64 + lane], f = p*2 + var.
//   var0: k<16 -> core_hi[q][p][r], k>=16 -> core_lo
//   var1: swapped halves
// A-frag layout (16x16x32): lane holds A[m=lane&15][k=(lane>>4)*8+j], j=0..7,
// packed 2 bf16/dword (even k in low half).
__global__ void build_frags(const float* __restrict__ cm, i32x4* __restrict__ fragbuf)
{
  const int t    = blockIdx.x;
  const int f    = threadIdx.x >> 6;   // 0..3
  const int lane = threadIdx.x & 63;
  const int r    = lane & 15;          // A row m == output bond index r
  const int g    = lane >> 4;
  const int p    = f >> 1;
  const int var  = f & 1;
  i32x4 w;
  #pragma unroll
  for(int d=0; d<4; ++d){
    u32 h[2];
    #pragma unroll
    for(int e=0; e<2; ++e){
      const int j = 2*d + e;
      const int k = g*8 + j;
      const int q = k & 15;
      const int lohalf = k >> 4;
      const float c = cm[ (((t*16 + q)*2) + p)*16 + r ];
      const u32 u  = __float_as_uint(c);
      const u32 a  = rne_bump(u);
      const float hif = __uint_as_float(a & 0xFFFF0000u);
      const u32 b  = rne_bump(__float_as_uint(c - hif));
      h[e] = (lohalf ^ var) ? (b >> 16) : (a >> 16);
    }
    w[d] = (int)(h[0] | (h[1] << 16));
  }
  fragbuf[(t*4 + f)*64 + lane] = w;
}

__global__ __launch_bounds__(256) void mps_chain(
  const float* __restrict__ phi,
  const float* __restrict__ core_first,
  const float* __restrict__ core_last,
  const float* __restrict__ bias,
  const i32x4* __restrict__ fragbuf,
  float* __restrict__ out)
{
  const int lane = threadIdx.x & 63;
  const int wv   = threadIdx.x >> 6;     // wave in block (4 waves/block)
  const int tile = blockIdx.x * 4 + wv;  // 16 samples per wave
  const int b0   = tile * 16;
  const int n    = lane & 15;            // this lane's sample column
  const int g    = lane >> 4;

  // wave-private LDS slice: [16 samples][LDS_ROW dwords]; dwords 0..7 = hi
  // plane (k=0..15), 8..15 = lo plane (k=16..31). No barriers needed.
  __shared__ int smem[4 * 16 * LDS_ROW];
  int* const myS  = smem + wv * (16 * LDS_ROW);
  int* const wrHi = myS + n * LDS_ROW + 2 * g;       // kpairs 2g, 2g+1
  int* const wrLo = wrHi + 8;
  const int* const rdP = myS + n * LDS_ROW + 4 * g;  // B-frag: kpairs 4g..4g+3

  const float* phiRow = phi + (size_t)(b0 + n) * 512;  // [L=256][2] per sample

  // v0[r] = phi[b,0,0]*core_first[0][r] + phi[b,0,1]*core_first[1][r]
  float v[4];
  {
    const float2 ph0 = *(const float2*)phiRow;
    #pragma unroll
    for(int reg=0; reg<4; ++reg){
      const int r = g*4 + reg;
      v[reg] = ph0.x * core_first[r] + ph0.y * core_first[16 + r];
    }
  }

  // split 4 state values (rows r=4g..4g+3 of column n) into bf16 hi/lo,
  // write hi dwords at kpairs 2g,2g+1 and lo dwords at 8+2g,8+2g+1
  auto split_write = [&](const float* vv){
    const u32 a0 = rne_bump(__float_as_uint(vv[0]));
    const u32 a1 = rne_bump(__float_as_uint(vv[1]));
    const u32 a2 = rne_bump(__float_as_uint(vv[2]));
    const u32 a3 = rne_bump(__float_as_uint(vv[3]));
    const float r0 = vv[0] - __uint_as_float(a0 & 0xFFFF0000u);
    const float r1 = vv[1] - __uint_as_float(a1 & 0xFFFF0000u);
    const float r2 = vv[2] - __uint_as_float(a2 & 0xFFFF0000u);
    const float r3 = vv[3] - __uint_as_float(a3 & 0xFFFF0000u);
    const u32 c0 = rne_bump(__float_as_uint(r0));
    const u32 c1 = rne_bump(__float_as_uint(r1));
    const u32 c2 = rne_bump(__float_as_uint(r2));
    const u32 c3 = rne_bump(__float_as_uint(r3));
    *(int2*)wrHi = make_int2((int)((a0 >> 16) | (a1 & 0xFFFF0000u)),
                             (int)((a2 >> 16) | (a3 & 0xFFFF0000u)));
    *(int2*)wrLo = make_int2((int)((c0 >> 16) | (c1 & 0xFFFF0000u)),
                             (int)((c2 >> 16) | (c3 & 0xFFFF0000u)));
  };

  split_write(v);
  i32x4 bfi = *(const i32x4*)rdP;

  // prefetch step-0 core fragments and phi for step 0 (phi[:, t+1])
  const i32x4* fb = fragbuf + lane;
  i32x4 af0 = fb[0*64], af1 = fb[1*64], af2 = fb[2*64], af3 = fb[3*64];
  float2 phn = *(const float2*)(phiRow + 2);

  #pragma unroll 1
  for(int t = 0; t < TMID; ++t){
    // prefetch next step (clamped at the end; t+2 <= 255 is always in-bounds)
    const int tn = (t < TMID-1) ? (t+1) : (TMID-1);
    const i32x4* fbn = fragbuf + tn*4*64 + lane;
    const i32x4 na0 = fbn[0], na1 = fbn[64], na2 = fbn[128], na3 = fbn[192];
    const float2 ph2 = *(const float2*)(phiRow + 2*(t+2));

    f32x4 acc0 = {0.f,0.f,0.f,0.f};
    f32x4 acc1 = {0.f,0.f,0.f,0.f};
    const bf16x8 bh = __builtin_bit_cast(bf16x8, bfi);
    acc0 = __builtin_amdgcn_mfma_f32_16x16x32_bf16(__builtin_bit_cast(bf16x8, af0), bh, acc0, 0,0,0);
    acc0 = __builtin_amdgcn_mfma_f32_16x16x32_bf16(__builtin_bit_cast(bf16x8, af1), bh, acc0, 0,0,0);
    acc1 = __builtin_amdgcn_mfma_f32_16x16x32_bf16(__builtin_bit_cast(bf16x8, af2), bh, acc1, 0,0,0);
    acc1 = __builtin_amdgcn_mfma_f32_16x16x32_bf16(__builtin_bit_cast(bf16x8, af3), bh, acc1, 0,0,0);

    // v_new[r][n] = phi0 * u_p0[r][n] + phi1 * u_p1[r][n]  (per-lane scalars)
    v[0] = phn.x*acc0[0] + phn.y*acc1[0];
    v[1] = phn.x*acc0[1] + phn.y*acc1[1];
    v[2] = phn.x*acc0[2] + phn.y*acc1[2];
    v[3] = phn.x*acc0[3] + phn.y*acc1[3];

    // stage next B operand (extra harmless pass on the last iteration)
    split_write(v);
    bfi = *(const i32x4*)rdP;

    af0 = na0; af1 = na1; af2 = na2; af3 = na3;
    phn = ph2;
  }

  // epilogue: out[n] = sum_r v[r][n] * (core_last[r][0]*phiL0 + core_last[r][1]*phiL1)
  const float2 phL = *(const float2*)(phiRow + 2*255);
  float part = 0.f;
  #pragma unroll
  for(int reg=0; reg<4; ++reg){
    const int r = g*4 + reg;
    part += v[reg] * (core_last[2*r] * phL.x + core_last[2*r + 1] * phL.y);
  }
  part += __shfl_xor(part, 16, 64);
  part += __shfl_xor(part, 32, 64);
  if(g == 0) out[b0 + n] = part + bias[0];
}

extern "C" void kernel_launch(void* const* d_in, const int* in_sizes, int n_in,
                              void* d_out, int out_size, void* d_ws, size_t ws_size,
                              hipStream_t stream)
{
  const float* phi  = (const float*)d_in[0];  // [32768,256,2]
  const float* cf   = (const float*)d_in[1];  // [2,16]
  const float* cm   = (const float*)d_in[2];  // [254,16,2,16]
  const float* cl   = (const float*)d_in[3];  // [16,2]
  const float* bias = (const float*)d_in[4];  // scalar
  i32x4* fragbuf = (i32x4*)d_ws;              // 254*4*64*16B = 1.04 MB

  build_frags<<<TMID, 256, 0, stream>>>(cm, fragbuf);
  mps_chain<<<512, 256, 0, stream>>>(phi, cf, cl, bias, fragbuf, (float*)d_out);
}

// Round 2
// 181.071 us; speedup vs baseline: 1.1478x; 1.1478x over previous
//
#include <hip/hip_runtime.h>
#include <stdint.h>

// MPS chain contraction, B=32768, L=256, D=16.
// Step GEMM: C[r][n] = sum_q core_p[q][r] * v[q][n]
//   A = core^T (shared, precomputed bf16 hi/lo fragments, RNE split)
//   B = per-sample state v, truncation hi/lo split packed along K=32
//   C layout col = lane&15 = sample n -> phi combine is per-lane scalar.
// C->B layout fix: rows redistribute across the 4 lanes with the same n.
// Done with 8 ds_bpermute + 4 cndmask (no LDS alloc, no write->read dep).

typedef short  bf16x8 __attribute__((ext_vector_type(8)));
typedef float  f32x4  __attribute__((ext_vector_type(4)));
typedef int    i32x4  __attribute__((ext_vector_type(4)));
typedef unsigned int u32;

#define TMID 254

#if __has_builtin(__builtin_amdgcn_perm)
#define PACK_HI(hi, lo) ((int)__builtin_amdgcn_perm((u32)(hi), (u32)(lo), 0x07060302u))
#else
#define PACK_HI(hi, lo) ((int)(((u32)(hi) & 0xFFFF0000u) | ((u32)(lo) >> 16)))
#endif

__device__ __forceinline__ u32 rne_bump(u32 u){
  return u + 0x7FFFu + ((u >> 16) & 1u);
}

// Prologue: per-step A-operand fragments from cores_mid (f32), RNE hi/lo.
// fragbuf[(t*4 + f)*64 + lane], f = p*2 + var.
//   var0: k<16 -> core_hi[q][p][r], k>=16 -> core_lo ; var1: halves swapped
// A-frag layout (16x16x32): lane holds A[m=lane&15][k=(lane>>4)*8+j], j=0..7,
// 2 bf16/dword, even k in low half.
__global__ void build_frags(const float* __restrict__ cm, i32x4* __restrict__ fragbuf)
{
  const int t    = blockIdx.x;
  const int f    = threadIdx.x >> 6;
  const int lane = threadIdx.x & 63;
  const int r    = lane & 15;
  const int g    = lane >> 4;
  const int p    = f >> 1;
  const int var  = f & 1;
  i32x4 w;
  #pragma unroll
  for(int d=0; d<4; ++d){
    u32 h[2];
    #pragma unroll
    for(int e=0; e<2; ++e){
      const int j = 2*d + e;
      const int k = g*8 + j;
      const int q = k & 15;
      const int lohalf = k >> 4;
      const float c = cm[ (((t*16 + q)*2) + p)*16 + r ];
      const u32 u  = __float_as_uint(c);
      const u32 a  = rne_bump(u);
      const float hif = __uint_as_float(a & 0xFFFF0000u);
      const u32 b  = rne_bump(__float_as_uint(c - hif));
      h[e] = (lohalf ^ var) ? (b >> 16) : (a >> 16);
    }
    w[d] = (int)(h[0] | (h[1] << 16));
  }
  fragbuf[(t*4 + f)*64 + lane] = w;
}

__global__ __launch_bounds__(256) void mps_chain(
  const float* __restrict__ phi,
  const float* __restrict__ core_first,
  const float* __restrict__ core_last,
  const float* __restrict__ bias,
  const i32x4* __restrict__ fragbuf,
  float* __restrict__ out)
{
  const int lane = threadIdx.x & 63;
  const int wv   = threadIdx.x >> 6;
  const int tile = blockIdx.x * 4 + wv;
  const int b0   = tile * 16;
  const int n    = lane & 15;          // sample column
  const int g    = lane >> 4;          // row group: holds C rows 4g..4g+3

  const bool hiSel = (g < 2);
  const int addrA  = (n + 32 * (g & 1)) << 2;  // bpermute byte addr, loop-invariant
  const int addrB  = addrA + 64;

  const float* phiRow = phi + (size_t)(b0 + n) * 512;

  // v0[r] = phi[b,0,0]*core_first[0][r] + phi[b,0,1]*core_first[1][r]
  float v[4];
  float4 f4a = *(const float4*)phiRow;   // idx0 (x,y) for v0; idx1 (z,w) for step 0
  #pragma unroll
  for(int reg=0; reg<4; ++reg){
    const int r = g*4 + reg;
    v[reg] = f4a.x * core_first[r] + f4a.y * core_first[16 + r];
  }

  // truncation hi/lo split + cross-lane redistribution into B-operand layout
  i32x4 bfrag;
  auto make_bfrag = [&](){
    const u32 u0 = __float_as_uint(v[0]), u1 = __float_as_uint(v[1]);
    const u32 u2 = __float_as_uint(v[2]), u3 = __float_as_uint(v[3]);
    const float l0 = v[0] - __uint_as_float(u0 & 0xFFFF0000u);
    const float l1 = v[1] - __uint_as_float(u1 & 0xFFFF0000u);
    const float l2 = v[2] - __uint_as_float(u2 & 0xFFFF0000u);
    const float l3 = v[3] - __uint_as_float(u3 & 0xFFFF0000u);
    const int hp01 = PACK_HI(u1, u0);
    const int hp23 = PACK_HI(u3, u2);
    const int lp01 = PACK_HI(__float_as_uint(l1), __float_as_uint(l0));
    const int lp23 = PACK_HI(__float_as_uint(l3), __float_as_uint(l2));
    const int ah0 = __builtin_amdgcn_ds_bpermute(addrA, hp01);
    const int ah1 = __builtin_amdgcn_ds_bpermute(addrA, hp23);
    const int al0 = __builtin_amdgcn_ds_bpermute(addrA, lp01);
    const int al1 = __builtin_amdgcn_ds_bpermute(addrA, lp23);
    const int bh0 = __builtin_amdgcn_ds_bpermute(addrB, hp01);
    const int bh1 = __builtin_amdgcn_ds_bpermute(addrB, hp23);
    const int bl0 = __builtin_amdgcn_ds_bpermute(addrB, lp01);
    const int bl1 = __builtin_amdgcn_ds_bpermute(addrB, lp23);
    bfrag[0] = hiSel ? ah0 : al0;
    bfrag[1] = hiSel ? ah1 : al1;
    bfrag[2] = hiSel ? bh0 : bl0;
    bfrag[3] = hiSel ? bh1 : bl1;
  };
  make_bfrag();

  // one MFMA step: consumes bfrag + frag set, produces new v and bfrag
  auto step = [&](const i32x4& a0, const i32x4& a1, const i32x4& a2,
                  const i32x4& a3, float phx, float phy){
    f32x4 acc0 = {0.f,0.f,0.f,0.f};
    f32x4 acc1 = {0.f,0.f,0.f,0.f};
    const bf16x8 bh = __builtin_bit_cast(bf16x8, bfrag);
    acc0 = __builtin_amdgcn_mfma_f32_16x16x32_bf16(__builtin_bit_cast(bf16x8, a0), bh, acc0, 0,0,0);
    acc0 = __builtin_amdgcn_mfma_f32_16x16x32_bf16(__builtin_bit_cast(bf16x8, a1), bh, acc0, 0,0,0);
    acc1 = __builtin_amdgcn_mfma_f32_16x16x32_bf16(__builtin_bit_cast(bf16x8, a2), bh, acc1, 0,0,0);
    acc1 = __builtin_amdgcn_mfma_f32_16x16x32_bf16(__builtin_bit_cast(bf16x8, a3), bh, acc1, 0,0,0);
    v[0] = phx*acc0[0] + phy*acc1[0];
    v[1] = phx*acc0[1] + phy*acc1[1];
    v[2] = phx*acc0[2] + phy*acc1[2];
    v[3] = phx*acc0[3] + phy*acc1[3];
    make_bfrag();
  };

  // preload frag sets for steps 0 and 1 (distance-2 rotating prefetch)
  const i32x4* fb = fragbuf + lane;
  i32x4 A0 = fb[0],   A1 = fb[64],  A2 = fb[128], A3 = fb[192];
  i32x4 B0 = fb[256], B1 = fb[320], B2 = fb[384], B3 = fb[448];

  #pragma unroll 1
  for(int t = 0; t < TMID; t += 2){
    // phi float4 at even idx t+2: covers combine idx for steps t+1 and t+2
    const float4 f4n = *(const float4*)(phiRow + 2*(t+2));

    step(A0, A1, A2, A3, f4a.z, f4a.w);          // step t (phi idx t+1)
    {
      const int tp = (t+2 < TMID) ? (t+2) : (TMID-1);
      const i32x4* fp = fragbuf + tp*256 + lane;
      A0 = fp[0]; A1 = fp[64]; A2 = fp[128]; A3 = fp[192];
    }
    step(B0, B1, B2, B3, f4n.x, f4n.y);          // step t+1 (phi idx t+2)
    {
      const int tp = (t+3 < TMID) ? (t+3) : (TMID-1);
      const i32x4* fp = fragbuf + tp*256 + lane;
      B0 = fp[0]; B1 = fp[64]; B2 = fp[128]; B3 = fp[192];
    }
    f4a = f4n;
  }

  // epilogue: f4a = phi idx 254 (z,w = idx 255)
  float part = 0.f;
  #pragma unroll
  for(int reg=0; reg<4; ++reg){
    const int r = g*4 + reg;
    part += v[reg] * (core_last[2*r] * f4a.z + core_last[2*r + 1] * f4a.w);
  }
  part += __shfl_xor(part, 16, 64);
  part += __shfl_xor(part, 32, 64);
  if(g == 0) out[b0 + n] = part + bias[0];
}

extern "C" void kernel_launch(void* const* d_in, const int* in_sizes, int n_in,
                              void* d_out, int out_size, void* d_ws, size_t ws_size,
                              hipStream_t stream)
{
  const float* phi  = (const float*)d_in[0];  // [32768,256,2]
  const float* cf   = (const float*)d_in[1];  // [2,16]
  const float* cm   = (const float*)d_in[2];  // [254,16,2,16]
  const float* cl   = (const float*)d_in[3];  // [16,2]
  const float* bias = (const float*)d_in[4];  // scalar
  i32x4* fragbuf = (i32x4*)d_ws;              // 254*4*64*16B = 1.04 MB

  build_frags<<<TMID, 256, 0, stream>>>(cm, fragbuf);
  mps_chain<<<512, 256, 0, stream>>>(phi, cf, cl, bias, fragbuf, (float*)d_out);
}

// Round 3
// 157.073 us; speedup vs baseline: 1.3232x; 1.1528x over previous
//
#include <hip/hip_runtime.h>
#include <stdint.h>

// MPS chain contraction, B=32768, L=256, D=16 — bidirectional split.
// out = v0^T M_0 ... M_253 z  =  f . b
//   f = (v0^T M_0..M_127)^T   forward chain, 128 steps
//   b = M_128..M_253 z        backward chain, 126 steps (bond idx swapped)
// Block = 4 waves over 32 samples: wv0,1 fwd / wv2,3 bwd; LDS dot epilogue.
// Step GEMM (both dirs): C[m][n] = sum_k A_p[m][k] * Bop[k][n]
//   A_p = shared core fragments (bf16 RNE hi in k<16, lo in k>=16)
//   B   = state split [vh; vl];  Bswap = [vl; vh]
//   u_p = A_p x B + A_p x Bswap  (exact (ch+cl)(vh+vl)); per-lane phi combine.
// C->B layout fix via 8 ds_bpermute + cndmask (no LDS round-trip).

typedef short  bf16x8 __attribute__((ext_vector_type(8)));
typedef float  f32x4  __attribute__((ext_vector_type(4)));
typedef int    i32x4  __attribute__((ext_vector_type(4)));
typedef unsigned int u32;

#define NFWD 128          // fwd slots: cores t=0..127
#define NBWD 126          // bwd slots: s=0..125 <-> cores t=253-s
#define BWD_OFF (NFWD*2*64)   // i32x4 offset of bwd table in ws

#if __has_builtin(__builtin_amdgcn_perm)
#define PACK_HI(hi, lo) ((int)__builtin_amdgcn_perm((u32)(hi), (u32)(lo), 0x07060302u))
#else
#define PACK_HI(hi, lo) ((int)(((u32)(hi) & 0xFFFF0000u) | ((u32)(lo) >> 16)))
#endif

__device__ __forceinline__ u32 rne_bump(u32 u){
  return u + 0x7FFFu + ((u >> 16) & 1u);
}

// A-frag layout (16x16x32): lane holds A[m=lane&15][k=(lane>>4)*8+j], j=0..7,
// 2 bf16/dword (even k low). k<16 -> RNE hi part, k>=16 -> RNE lo part.
// fwd: A_p[m][k] from cm[t][q=k&15][p][r=m]; bwd: from cm[t][q=m][p][r=k&15].
__global__ void build_frags(const float* __restrict__ cm, i32x4* __restrict__ ws)
{
  const int bid  = blockIdx.x;          // 0..127 fwd, 128..253 bwd
  const int p    = threadIdx.x >> 6;    // 0,1 (block = 128 threads)
  const int lane = threadIdx.x & 63;
  const int m    = lane & 15;
  const int g    = lane >> 4;
  const bool fwd = bid < NFWD;
  const int slot = fwd ? bid : (bid - NFWD);
  const int t    = fwd ? bid : (253 - slot);
  i32x4* dst = ws + (fwd ? 0 : BWD_OFF) + (slot*2 + p)*64 + lane;
  i32x4 w;
  #pragma unroll
  for(int d=0; d<4; ++d){
    u32 h[2];
    #pragma unroll
    for(int e=0; e<2; ++e){
      const int j = 2*d + e;
      const int k = g*8 + j;
      const int q = k & 15;
      const int lohalf = k >> 4;
      const int ci = fwd ? ((((t*16 + q)*2) + p)*16 + m)
                         : ((((t*16 + m)*2) + p)*16 + q);
      const float c = cm[ci];
      const u32 u  = __float_as_uint(c);
      const u32 a  = rne_bump(u);
      const float hif = __uint_as_float(a & 0xFFFF0000u);
      const u32 b  = rne_bump(__float_as_uint(c - hif));
      h[e] = lohalf ? (b >> 16) : (a >> 16);
    }
    w[d] = (int)(h[0] | (h[1] << 16));
  }
  *dst = w;
}

__global__ __launch_bounds__(256) void mps_chain(
  const float* __restrict__ phi,
  const float* __restrict__ core_first,
  const float* __restrict__ core_last,
  const float* __restrict__ bias,
  const i32x4* __restrict__ ws,
  float* __restrict__ out)
{
  const int lane = threadIdx.x & 63;
  const int wv   = threadIdx.x >> 6;
  const int b0   = blockIdx.x * 32;
  const int n    = lane & 15;              // sample column within wave
  const int g    = lane >> 4;              // row group (C rows 4g..4g+3)
  const int s_in = (wv & 1)*16 + n;        // sample index within block
  const bool isFwd = (wv < 2);
  const bool hiSel = (g < 2);
  const int addrA  = (n + 32*(g & 1)) << 2;
  const int addrB  = addrA + 64;

  const float* phiRow = phi + (size_t)(b0 + s_in) * 512;

  __shared__ float red[2][32][20];         // [f|b][sample][16 bond + pad]

  float v[4];
  i32x4 bfrag, bswap;

  auto make_bfrag = [&](){
    const u32 u0 = __float_as_uint(v[0]), u1 = __float_as_uint(v[1]);
    const u32 u2 = __float_as_uint(v[2]), u3 = __float_as_uint(v[3]);
    const float l0 = v[0] - __uint_as_float(u0 & 0xFFFF0000u);
    const float l1 = v[1] - __uint_as_float(u1 & 0xFFFF0000u);
    const float l2 = v[2] - __uint_as_float(u2 & 0xFFFF0000u);
    const float l3 = v[3] - __uint_as_float(u3 & 0xFFFF0000u);
    const int hp01 = PACK_HI(u1, u0);
    const int hp23 = PACK_HI(u3, u2);
    const int lp01 = PACK_HI(__float_as_uint(l1), __float_as_uint(l0));
    const int lp23 = PACK_HI(__float_as_uint(l3), __float_as_uint(l2));
    const int ah0 = __builtin_amdgcn_ds_bpermute(addrA, hp01);
    const int ah1 = __builtin_amdgcn_ds_bpermute(addrA, hp23);
    const int al0 = __builtin_amdgcn_ds_bpermute(addrA, lp01);
    const int al1 = __builtin_amdgcn_ds_bpermute(addrA, lp23);
    const int bh0 = __builtin_amdgcn_ds_bpermute(addrB, hp01);
    const int bh1 = __builtin_amdgcn_ds_bpermute(addrB, hp23);
    const int bl0 = __builtin_amdgcn_ds_bpermute(addrB, lp01);
    const int bl1 = __builtin_amdgcn_ds_bpermute(addrB, lp23);
    bfrag[0] = hiSel ? ah0 : al0;   bswap[0] = hiSel ? al0 : ah0;
    bfrag[1] = hiSel ? ah1 : al1;   bswap[1] = hiSel ? al1 : ah1;
    bfrag[2] = hiSel ? bh0 : bl0;   bswap[2] = hiSel ? bl0 : bh0;
    bfrag[3] = hiSel ? bh1 : bl1;   bswap[3] = hiSel ? bl1 : bh1;
  };

  auto step = [&](const i32x4& a0, const i32x4& a1, float phx, float phy){
    f32x4 acc0 = {0.f,0.f,0.f,0.f};
    f32x4 acc1 = {0.f,0.f,0.f,0.f};
    const bf16x8 bh = __builtin_bit_cast(bf16x8, bfrag);
    const bf16x8 bs = __builtin_bit_cast(bf16x8, bswap);
    acc0 = __builtin_amdgcn_mfma_f32_16x16x32_bf16(__builtin_bit_cast(bf16x8, a0), bh, acc0, 0,0,0);
    acc0 = __builtin_amdgcn_mfma_f32_16x16x32_bf16(__builtin_bit_cast(bf16x8, a0), bs, acc0, 0,0,0);
    acc1 = __builtin_amdgcn_mfma_f32_16x16x32_bf16(__builtin_bit_cast(bf16x8, a1), bh, acc1, 0,0,0);
    acc1 = __builtin_amdgcn_mfma_f32_16x16x32_bf16(__builtin_bit_cast(bf16x8, a1), bs, acc1, 0,0,0);
    v[0] = phx*acc0[0] + phy*acc1[0];
    v[1] = phx*acc0[1] + phy*acc1[1];
    v[2] = phx*acc0[2] + phy*acc1[2];
    v[3] = phx*acc0[3] + phy*acc1[3];
    make_bfrag();
  };

  if (isFwd){
    const i32x4* tab = ws;                       // slots 0..127
    float4 f4a = *(const float4*)phiRow;         // phi[0] (x,y), phi[1] (z,w)
    #pragma unroll
    for(int reg=0; reg<4; ++reg){
      const int r = g*4 + reg;
      v[reg] = f4a.x * core_first[r] + f4a.y * core_first[16 + r];
    }
    make_bfrag();
    i32x4 P0 = tab[lane],       P1 = tab[64 + lane];        // slot 0
    i32x4 Q0 = tab[128 + lane], Q1 = tab[192 + lane];       // slot 1
    #pragma unroll 1
    for(int t = 0; t < NFWD; t += 2){
      const float4 f4n = *(const float4*)(phiRow + 2*(t+2));  // phi[t+2],[t+3]
      step(P0, P1, f4a.z, f4a.w);                 // step t, coeff phi[t+1]
      {
        const int sp = (t+2 < NFWD) ? (t+2) : (NFWD-1);
        P0 = tab[sp*128 + lane]; P1 = tab[sp*128 + 64 + lane];
      }
      step(Q0, Q1, f4n.x, f4n.y);                 // step t+1, coeff phi[t+2]
      {
        const int sq = (t+3 < NFWD) ? (t+3) : (NFWD-1);
        Q0 = tab[sq*128 + lane]; Q1 = tab[sq*128 + 64 + lane];
      }
      f4a = f4n;
    }
  } else {
    const i32x4* tab = ws + BWD_OFF;             // slots 0..125 (t=253-s)
    float4 f4a = *(const float4*)(phiRow + 508); // phi[254] (x,y), phi[255] (z,w)
    #pragma unroll
    for(int reg=0; reg<4; ++reg){
      const int r = g*4 + reg;
      v[reg] = f4a.z * core_last[2*r] + f4a.w * core_last[2*r + 1];  // z-init
    }
    make_bfrag();
    i32x4 P0 = tab[lane],       P1 = tab[64 + lane];
    i32x4 Q0 = tab[128 + lane], Q1 = tab[192 + lane];
    float cx = f4a.x, cy = f4a.y;                // step s=0 coeff = phi[254]
    #pragma unroll 1
    for(int s = 0; s < NBWD; s += 2){
      const float4 f4n = *(const float4*)(phiRow + 2*(252-s)); // phi[252-s],[253-s]
      step(P0, P1, cx, cy);                       // step s, coeff phi[254-s]
      {
        const int sp = (s+2 < NBWD) ? (s+2) : (NBWD-1);
        P0 = tab[sp*128 + lane]; P1 = tab[sp*128 + 64 + lane];
      }
      step(Q0, Q1, f4n.z, f4n.w);                 // step s+1, coeff phi[253-s]
      {
        const int sq = (s+3 < NBWD) ? (s+3) : (NBWD-1);
        Q0 = tab[sq*128 + lane]; Q1 = tab[sq*128 + 64 + lane];
      }
      cx = f4n.x; cy = f4n.y;                     // step s+2 coeff = phi[252-s]
    }
  }

  // epilogue: deposit f / b vectors, block dot
  *(float4*)&red[isFwd ? 0 : 1][s_in][4*g] = make_float4(v[0], v[1], v[2], v[3]);
  __syncthreads();
  if (threadIdx.x < 32){
    const int s = threadIdx.x;
    float acc = bias[0];
    #pragma unroll
    for(int q = 0; q < 16; ++q)
      acc += red[0][s][q] * red[1][s][q];
    out[b0 + s] = acc;
  }
}

extern "C" void kernel_launch(void* const* d_in, const int* in_sizes, int n_in,
                              void* d_out, int out_size, void* d_ws, size_t ws_size,
                              hipStream_t stream)
{
  const float* phi  = (const float*)d_in[0];  // [32768,256,2]
  const float* cf   = (const float*)d_in[1];  // [2,16]
  const float* cm   = (const float*)d_in[2];  // [254,16,2,16]
  const float* cl   = (const float*)d_in[3];  // [16,2]
  const float* bias = (const float*)d_in[4];  // scalar
  i32x4* ws = (i32x4*)d_ws;                   // (128+126)*2*64*16B = 508 KB

  build_frags<<<254, 128, 0, stream>>>(cm, ws);
  mps_chain<<<1024, 256, 0, stream>>>(phi, cf, cl, bias, ws, (float*)d_out);
}